// Round 9
// baseline (2379.241 us; speedup 1.0000x reference)
//
#include <hip/hip_runtime.h>
#include <hip/hip_bf16.h>

#define HDIM 128
#define G3 384          // 3*H
#define EDIM 300
#define BATCH 64
#define LSTO 1024
#define QLEN 32
#define NSENT 16
#define WGB 16          // batches per scan workgroup
#define HPAD 136        // h_lds row stride in bf16 (272B, conflict-free b128)

typedef float4 f4;
typedef __attribute__((ext_vector_type(8))) short bf16x8;
typedef __attribute__((ext_vector_type(4))) float f32x4;

__device__ __forceinline__ float sigmf(float x) { return 1.0f / (1.0f + __expf(-x)); }
__device__ __forceinline__ float tanhfast(float x) {
    float e = __expf(-2.0f * x);
    return (1.0f - e) / (1.0f + e);
}
__device__ __forceinline__ float bf2f(unsigned short u) {
    return __uint_as_float(((unsigned)u) << 16);
}
__device__ __forceinline__ short f2bf_s(float f) {
    union { __hip_bfloat16 b; short s; } u;
    u.b = __float2bfloat16(f);
    return u.s;
}
__device__ __forceinline__ bf16x8 packrow8(const float* p) {
    bf16x8 v;
#pragma unroll
    for (int i = 0; i < 8; i++) v[i] = f2bf_s(p[i]);
    return v;
}

// ---------------------------------------------------------------------------
// K1: gi[row][g] = b_ih[g] + emb[tok[row]] . w_ih[g]   (K = 300), bf16 out
// ---------------------------------------------------------------------------
__global__ __launch_bounds__(192) void k_gi_gather(
    const int* __restrict__ toks, int nrows,
    const float* __restrict__ emb,
    const float* __restrict__ w_ih, const float* __restrict__ b_ih,
    __hip_bfloat16* __restrict__ gi)
{
    __shared__ alignas(16) float a_lds[32 * EDIM];
    int tid = threadIdx.x;
    int rowbase = blockIdx.x * 32;

    for (int i = tid; i < 32 * 75; i += 192) {   // 75 = 300/4
        int r = i / 75, e4 = i - r * 75;
        int row = rowbase + r;
        int tok = (row < nrows) ? toks[row] : 0;
        f4 v = *reinterpret_cast<const f4*>(emb + (size_t)tok * EDIM + e4 * 4);
        *reinterpret_cast<f4*>(a_lds + r * EDIM + e4 * 4) = v;
    }
    __syncthreads();

    int g0 = tid, g1 = tid + 192;
    float acc0[32], acc1[32];
#pragma unroll
    for (int r = 0; r < 32; r++) { acc0[r] = 0.f; acc1[r] = 0.f; }

    const float* w0p = w_ih + (size_t)g0 * EDIM;
    const float* w1p = w_ih + (size_t)g1 * EDIM;
    for (int e4 = 0; e4 < 75; ++e4) {
        f4 w0 = *reinterpret_cast<const f4*>(w0p + e4 * 4);
        f4 w1 = *reinterpret_cast<const f4*>(w1p + e4 * 4);
#pragma unroll
        for (int r = 0; r < 32; r++) {
            f4 a = *reinterpret_cast<const f4*>(a_lds + r * EDIM + e4 * 4);
            acc0[r] += a.x * w0.x + a.y * w0.y + a.z * w0.z + a.w * w0.w;
            acc1[r] += a.x * w1.x + a.y * w1.y + a.z * w1.z + a.w * w1.w;
        }
    }
    float bb0 = b_ih[g0], bb1 = b_ih[g1];
    for (int r = 0; r < 32; r++) {
        int row = rowbase + r;
        if (row < nrows) {
            gi[(size_t)row * G3 + g0] = __float2bfloat16(acc0[r] + bb0);
            gi[(size_t)row * G3 + g1] = __float2bfloat16(acc1[r] + bb1);
        }
    }
}

// ---------------------------------------------------------------------------
// K1b: dense variant, K = 128 (episodic gi from sents)
// ---------------------------------------------------------------------------
__global__ __launch_bounds__(192) void k_gi_dense(
    const float* __restrict__ x, int nrows,
    const float* __restrict__ w_ih, const float* __restrict__ b_ih,
    __hip_bfloat16* __restrict__ gi)
{
    __shared__ alignas(16) float a_lds[32 * HDIM];
    int tid = threadIdx.x;
    int rowbase = blockIdx.x * 32;

    for (int i = tid; i < 32 * 32; i += 192) {   // 32 = 128/4
        int r = i >> 5, e4 = i & 31;
        int row = rowbase + r;
        f4 v;
        if (row < nrows) v = *reinterpret_cast<const f4*>(x + (size_t)row * HDIM + e4 * 4);
        else { v.x = v.y = v.z = v.w = 0.f; }
        *reinterpret_cast<f4*>(a_lds + r * HDIM + e4 * 4) = v;
    }
    __syncthreads();

    int g0 = tid, g1 = tid + 192;
    float acc0[32], acc1[32];
#pragma unroll
    for (int r = 0; r < 32; r++) { acc0[r] = 0.f; acc1[r] = 0.f; }

    const float* w0p = w_ih + (size_t)g0 * HDIM;
    const float* w1p = w_ih + (size_t)g1 * HDIM;
    for (int e4 = 0; e4 < 32; ++e4) {
        f4 w0 = *reinterpret_cast<const f4*>(w0p + e4 * 4);
        f4 w1 = *reinterpret_cast<const f4*>(w1p + e4 * 4);
#pragma unroll
        for (int r = 0; r < 32; r++) {
            f4 a = *reinterpret_cast<const f4*>(a_lds + r * HDIM + e4 * 4);
            acc0[r] += a.x * w0.x + a.y * w0.y + a.z * w0.z + a.w * w0.w;
            acc1[r] += a.x * w1.x + a.y * w1.y + a.z * w1.z + a.w * w1.w;
        }
    }
    float bb0 = b_ih[g0], bb1 = b_ih[g1];
    for (int r = 0; r < 32; r++) {
        int row = rowbase + r;
        if (row < nrows) {
            gi[(size_t)row * G3 + g0] = __float2bfloat16(acc0[r] + bb0);
            gi[(size_t)row * G3 + g1] = __float2bfloat16(acc1[r] + bb1);
        }
    }
}

// ---------------------------------------------------------------------------
// K2: MFMA-batched GRU scan. 4 WGs x 16 batches, 512 threads (8 waves).
// Per step: gh(16x384) = h(16x128) @ W^T via mfma_f32_16x16x32_bf16.
// Wave w owns n-tiles {w, 8+w, 16+w} -> gates {j, 128+j, 256+j}, j=16w+(l&15):
// all 3 gates of h-elem j land in this lane's accs (C/D: col=l&15,
// row=(l>>4)*4+q). B-frags: 12 x bf16x8 = 48 VGPR, loaded once, pinned.
// h: bf16 in LDS [16][HPAD] for A-frags; f32 carried in per-lane regs.
// ---------------------------------------------------------------------------
template <int MODE>
__global__ __launch_bounds__(512, 1) void k_scan(
    const __hip_bfloat16* __restrict__ gi,   // [BATCH*T][384]
    int T,
    const float* __restrict__ w_hh, const float* __restrict__ b_hh,
    const int* __restrict__ mask,            // MODE 0
    float* __restrict__ sents,               // MODE 0
    const int* __restrict__ qtoks,           // MODE 1
    float* __restrict__ qv_out,              // MODE 1 (d_out)
    float* __restrict__ q_ws,                // MODE 1
    const float* __restrict__ gates,         // MODE 2
    float* __restrict__ h_out,               // MODE 2 (mem ws)
    float* __restrict__ ep_out)              // MODE 2 (d_out, nullable)
{
    __shared__ __hip_bfloat16 h_lds[WGB * HPAD];

    const int tid = threadIdx.x;
    const int w   = tid >> 6;        // wave 0..7
    const int l   = tid & 63;
    const int col = l & 15;          // n within tile == A row m
    const int kg  = l >> 4;          // 0..3
    const int b0  = blockIdx.x * WGB;
    const int j   = 16 * w + col;    // h-element / r-gate index
    const int m0  = kg * 4;          // this lane's first batch row

    // ---- B fragments: B[k][n] = w_hh[gate][k]; lane: 8 consecutive k ----
    const float* wr = w_hh + (size_t)j * HDIM + kg * 8;
    const float* wz = w_hh + (size_t)(128 + j) * HDIM + kg * 8;
    const float* wn = w_hh + (size_t)(256 + j) * HDIM + kg * 8;
    bf16x8 Br0 = packrow8(wr +  0), Br1 = packrow8(wr + 32),
           Br2 = packrow8(wr + 64), Br3 = packrow8(wr + 96);
    bf16x8 Bz0 = packrow8(wz +  0), Bz1 = packrow8(wz + 32),
           Bz2 = packrow8(wz + 64), Bz3 = packrow8(wz + 96);
    bf16x8 Bn0 = packrow8(wn +  0), Bn1 = packrow8(wn + 32),
           Bn2 = packrow8(wn + 64), Bn3 = packrow8(wn + 96);
    asm volatile("" : "+v"(Br0), "+v"(Br1), "+v"(Br2), "+v"(Br3));
    asm volatile("" : "+v"(Bz0), "+v"(Bz1), "+v"(Bz2), "+v"(Bz3));
    asm volatile("" : "+v"(Bn0), "+v"(Bn1), "+v"(Bn2), "+v"(Bn3));

    const float bias_r = b_hh[j], bias_z = b_hh[128 + j], bias_n = b_hh[256 + j];

    for (int i = tid; i < WGB * HPAD; i += 512) h_lds[i] = __float2bfloat16(0.f);

    float hp[4] = {0.f, 0.f, 0.f, 0.f};
    int scnt[4] = {0, 0, 0, 0};
    int qi[4];
    if (MODE == 1) {
#pragma unroll
        for (int q = 0; q < 4; q++) {
            qi[q] = QLEN - 1;
            for (int t2 = 0; t2 < QLEN - 1; t2++) {
                if (qtoks[(b0 + m0 + q) * QLEN + t2 + 1] == 0) { qi[q] = t2; break; }
            }
        }
    }

    // prefetch gi(t=0) (+mask/gates)
    unsigned short cr[4], cz[4], cn[4];
    int cm[4] = {0, 0, 0, 0};
    float cw[4] = {0.f, 0.f, 0.f, 0.f};
#pragma unroll
    for (int q = 0; q < 4; q++) {
        const unsigned short* gp = reinterpret_cast<const unsigned short*>(
            gi + ((size_t)(b0 + m0 + q) * T) * G3);
        cr[q] = gp[j]; cz[q] = gp[128 + j]; cn[q] = gp[256 + j];
        if (MODE == 0) cm[q] = mask[(b0 + m0 + q) * LSTO];
        if (MODE == 2) cw[q] = gates[(b0 + m0 + q) * NSENT];
    }
    __syncthreads();

    for (int t = 0; t < T; ++t) {
        // ---- A-fragments: A[m=col][k = kk*32 + kg*8 + i] ----
        const __hip_bfloat16* ar = h_lds + col * HPAD + kg * 8;
        bf16x8 A0 = *reinterpret_cast<const bf16x8*>(ar);
        bf16x8 A1 = *reinterpret_cast<const bf16x8*>(ar + 32);
        bf16x8 A2 = *reinterpret_cast<const bf16x8*>(ar + 64);
        bf16x8 A3 = *reinterpret_cast<const bf16x8*>(ar + 96);

        // ---- prefetch next step's gi while MFMA runs ----
        unsigned short nr[4], nz[4], nn[4];
        int nm[4] = {0, 0, 0, 0};
        float nw[4] = {0.f, 0.f, 0.f, 0.f};
        if (t + 1 < T) {
#pragma unroll
            for (int q = 0; q < 4; q++) {
                const unsigned short* gp = reinterpret_cast<const unsigned short*>(
                    gi + ((size_t)(b0 + m0 + q) * T + (t + 1)) * G3);
                nr[q] = gp[j]; nz[q] = gp[128 + j]; nn[q] = gp[256 + j];
                if (MODE == 0) nm[q] = mask[(b0 + m0 + q) * LSTO + t + 1];
                if (MODE == 2) nw[q] = gates[(b0 + m0 + q) * NSENT + t + 1];
            }
        }

        // ---- MFMA: gh = h @ W^T + b, K-chained over 4 x 32 ----
        f32x4 accr = {bias_r, bias_r, bias_r, bias_r};
        f32x4 accz = {bias_z, bias_z, bias_z, bias_z};
        f32x4 accn = {bias_n, bias_n, bias_n, bias_n};
        accr = __builtin_amdgcn_mfma_f32_16x16x32_bf16(A0, Br0, accr, 0, 0, 0);
        accr = __builtin_amdgcn_mfma_f32_16x16x32_bf16(A1, Br1, accr, 0, 0, 0);
        accr = __builtin_amdgcn_mfma_f32_16x16x32_bf16(A2, Br2, accr, 0, 0, 0);
        accr = __builtin_amdgcn_mfma_f32_16x16x32_bf16(A3, Br3, accr, 0, 0, 0);
        accz = __builtin_amdgcn_mfma_f32_16x16x32_bf16(A0, Bz0, accz, 0, 0, 0);
        accz = __builtin_amdgcn_mfma_f32_16x16x32_bf16(A1, Bz1, accz, 0, 0, 0);
        accz = __builtin_amdgcn_mfma_f32_16x16x32_bf16(A2, Bz2, accz, 0, 0, 0);
        accz = __builtin_amdgcn_mfma_f32_16x16x32_bf16(A3, Bz3, accz, 0, 0, 0);
        accn = __builtin_amdgcn_mfma_f32_16x16x32_bf16(A0, Bn0, accn, 0, 0, 0);
        accn = __builtin_amdgcn_mfma_f32_16x16x32_bf16(A1, Bn1, accn, 0, 0, 0);
        accn = __builtin_amdgcn_mfma_f32_16x16x32_bf16(A2, Bn2, accn, 0, 0, 0);
        accn = __builtin_amdgcn_mfma_f32_16x16x32_bf16(A3, Bn3, accn, 0, 0, 0);

        // ---- pointwise GRU cell, fully in-register (4 cells/lane) ----
#pragma unroll
        for (int q = 0; q < 4; q++) {
            float r = sigmf(bf2f(cr[q]) + accr[q]);
            float z = sigmf(bf2f(cz[q]) + accz[q]);
            float n = tanhfast(bf2f(cn[q]) + r * accn[q]);
            float hn = (1.f - z) * n + z * hp[q];
            if (MODE == 2) hn = cw[q] * hn + (1.f - cw[q]) * hp[q];
            hp[q] = hn;
        }
        __syncthreads();   // all waves' A-reads for step t are complete

#pragma unroll
        for (int q = 0; q < 4; q++)
            h_lds[(m0 + q) * HPAD + j] = __float2bfloat16(hp[q]);

        if (MODE == 0) {
#pragma unroll
            for (int q = 0; q < 4; q++) {
                if (cm[q]) {
                    if (scnt[q] < NSENT)
                        sents[((size_t)(b0 + m0 + q) * NSENT + scnt[q]) * HDIM + j] = hp[q];
                    scnt[q]++;
                }
            }
        }
        if (MODE == 1) {
#pragma unroll
            for (int q = 0; q < 4; q++) {
                if (t == qi[q]) {
                    qv_out[(b0 + m0 + q) * HDIM + j] = hp[q];
                    q_ws [(b0 + m0 + q) * HDIM + j] = hp[q];
                }
            }
        }
        if (MODE == 2 && t == T - 1) {
#pragma unroll
            for (int q = 0; q < 4; q++) {
                h_out[(b0 + m0 + q) * HDIM + j] = hp[q];
                if (ep_out) ep_out[(b0 + m0 + q) * HDIM + j] = hp[q];
            }
        }
        __syncthreads();

        if (t + 1 < T) {
#pragma unroll
            for (int q = 0; q < 4; q++) {
                cr[q] = nr[q]; cz[q] = nz[q]; cn[q] = nn[q];
                if (MODE == 0) cm[q] = nm[q];
                if (MODE == 2) cw[q] = nw[q];
            }
        }
    }
}

// ---------------------------------------------------------------------------
// K3: attention gates.  WG per batch, 128 threads = (16 t) x (8 segments).
// ---------------------------------------------------------------------------
__global__ __launch_bounds__(128) void k_gates(
    const float* __restrict__ sents, const float* __restrict__ q_ws,
    const float* __restrict__ mem, const float* __restrict__ gate_w,
    const float* __restrict__ gate_b,
    float* __restrict__ gates_ws, float* __restrict__ gout)
{
    int b = blockIdx.x, tid = threadIdx.x;
    int t = tid >> 3, s = tid & 7;
    float p = 0.f;
    const float* sv = sents + ((size_t)b * NSENT + t) * HDIM;
    for (int jj = 0; jj < 16; jj++) {
        int j = s * 16 + jj;
        float S = sv[j], Q = q_ws[b * HDIM + j], M = mem[b * HDIM + j];
        float dq = S - Q, dm = S - M;
        p += (S * Q) * gate_w[j] + (S * M) * gate_w[HDIM + j] +
             (dq * dq) * gate_w[2 * HDIM + j] + (dm * dm) * gate_w[3 * HDIM + j];
    }
    __shared__ float red[16][8];
    red[t][s] = p;
    __syncthreads();
    if (s == 0) {
        float sum = 0.f;
        for (int k = 0; k < 8; k++) sum += red[t][k];
        float gt = sigmf(sum + gate_b[0]);
        gates_ws[b * NSENT + t] = gt;
        if (gout) gout[b * NSENT + t] = gt;
    }
}

// ---------------------------------------------------------------------------
extern "C" void kernel_launch(void* const* d_in, const int* in_sizes, int n_in,
                              void* d_out, int out_size, void* d_ws, size_t ws_size,
                              hipStream_t stream)
{
    const int*   x_sto    = (const int*)d_in[0];
    const int*   x_mask   = (const int*)d_in[1];
    const int*   x_q      = (const int*)d_in[2];
    const float* emb      = (const float*)d_in[4];
    const float* enc_w_ih = (const float*)d_in[5];
    const float* enc_w_hh = (const float*)d_in[6];
    const float* enc_b_ih = (const float*)d_in[7];
    const float* enc_b_hh = (const float*)d_in[8];
    const float* gate_w   = (const float*)d_in[9];
    const float* gate_b   = (const float*)d_in[10];
    const float* ep_w_ih  = (const float*)d_in[11];
    const float* ep_w_hh  = (const float*)d_in[12];
    const float* ep_b_ih  = (const float*)d_in[13];
    const float* ep_b_hh  = (const float*)d_in[14];

    float* out_q  = (float*)d_out;                       // (64,128)
    float* out_ep = (float*)d_out + BATCH * HDIM;        // (1,64,128)
    float* out_g  = (float*)d_out + 2 * BATCH * HDIM;    // (64,16)

    char* ws = (char*)d_ws;
    size_t off = 0;
    auto alloc = [&](size_t bytes) {
        void* p = ws + off;
        off += (bytes + 255) & ~(size_t)255;
        return p;
    };
    __hip_bfloat16* gi_sto = (__hip_bfloat16*)alloc((size_t)BATCH * LSTO * G3 * 2);
    __hip_bfloat16* gi_q   = (__hip_bfloat16*)alloc((size_t)BATCH * QLEN * G3 * 2);
    __hip_bfloat16* gi_ep  = (__hip_bfloat16*)alloc((size_t)BATCH * NSENT * G3 * 2);
    float* sents    = (float*)alloc((size_t)BATCH * NSENT * HDIM * 4);
    float* q_ws     = (float*)alloc((size_t)BATCH * HDIM * 4);
    float* mem      = (float*)alloc((size_t)BATCH * HDIM * 4);
    float* gates_ws = (float*)alloc((size_t)BATCH * NSENT * 4);
    (void)ws_size; (void)in_sizes; (void)n_in; (void)out_size;

    // Phase A: input-projection GEMMs (gather + matmul), bf16 output
    k_gi_gather<<<(BATCH * LSTO) / 32, 192, 0, stream>>>(
        x_sto, BATCH * LSTO, emb, enc_w_ih, enc_b_ih, gi_sto);
    k_gi_gather<<<(BATCH * QLEN) / 32, 192, 0, stream>>>(
        x_q, BATCH * QLEN, emb, enc_w_ih, enc_b_ih, gi_q);

    // Phase B: story scan (writes sents), question scan (writes q_vecs)
    k_scan<0><<<BATCH / WGB, 512, 0, stream>>>(
        gi_sto, LSTO, enc_w_hh, enc_b_hh,
        x_mask, sents, nullptr, nullptr, nullptr, nullptr, nullptr, nullptr);
    k_scan<1><<<BATCH / WGB, 512, 0, stream>>>(
        gi_q, QLEN, enc_w_hh, enc_b_hh,
        nullptr, nullptr, x_q, out_q, q_ws, nullptr, nullptr, nullptr);

    // Phase C: episodic memory, 3 iterations
    k_gi_dense<<<(BATCH * NSENT) / 32, 192, 0, stream>>>(
        sents, BATCH * NSENT, ep_w_ih, ep_b_ih, gi_ep);

    for (int it = 0; it < 3; ++it) {
        const float* msrc = (it == 0) ? q_ws : mem;
        k_gates<<<BATCH, 128, 0, stream>>>(
            sents, q_ws, msrc, gate_w, gate_b, gates_ws,
            (it == 2) ? out_g : nullptr);
        k_scan<2><<<BATCH / WGB, 512, 0, stream>>>(
            gi_ep, NSENT, ep_w_hh, ep_b_hh,
            nullptr, nullptr, nullptr, nullptr, nullptr,
            gates_ws, mem, (it == 2) ? out_ep : nullptr);
    }
}

// Round 11
// 1799.284 us; speedup vs baseline: 1.3223x; 1.3223x over previous
//
#include <hip/hip_runtime.h>
#include <hip/hip_bf16.h>

#define HDIM 128
#define G3 384          // 3*H
#define EDIM 300
#define BATCH 64
#define LSTO 1024
#define QLEN 32
#define NSENT 16
#define WGB 16          // batches per scan workgroup

typedef float4 f4;
typedef __attribute__((ext_vector_type(8))) short bf16x8;
typedef __attribute__((ext_vector_type(4))) float f32x4;

__device__ __forceinline__ float sigmf(float x) { return 1.0f / (1.0f + __expf(-x)); }
__device__ __forceinline__ float tanhfast(float x) {
    float e = __expf(-2.0f * x);
    return (1.0f - e) / (1.0f + e);
}
__device__ __forceinline__ float bf2f(unsigned short u) {
    return __uint_as_float(((unsigned)u) << 16);
}
__device__ __forceinline__ unsigned short f2bf_u(float f) {
    union { __hip_bfloat16 b; unsigned short s; } u;
    u.b = __float2bfloat16(f);
    return u.s;
}
__device__ __forceinline__ short f2bf_s(float f) {
    union { __hip_bfloat16 b; short s; } u;
    u.b = __float2bfloat16(f);
    return u.s;
}
__device__ __forceinline__ bf16x8 packrow8(const float* p) {
    bf16x8 v;
#pragma unroll
    for (int i = 0; i < 8; i++) v[i] = f2bf_s(p[i]);
    return v;
}
__device__ __forceinline__ unsigned pack2bf(float a, float b) {
    return ((unsigned)f2bf_u(b) << 16) | (unsigned)f2bf_u(a);
}
__device__ __forceinline__ void barrier_nodrain() {
    asm volatile("" ::: "memory");
    __builtin_amdgcn_s_barrier();
    asm volatile("" ::: "memory");
}
__device__ __forceinline__ void lgkm0() {
    asm volatile("s_waitcnt lgkmcnt(0)" ::: "memory");
    __builtin_amdgcn_sched_barrier(0);
}

// ---------------------------------------------------------------------------
// K1: gi[row][g] = b_ih[g] + emb[tok[row]] . w_ih[g]   (K = 300), bf16 out
// ---------------------------------------------------------------------------
__global__ __launch_bounds__(192) void k_gi_gather(
    const int* __restrict__ toks, int nrows,
    const float* __restrict__ emb,
    const float* __restrict__ w_ih, const float* __restrict__ b_ih,
    __hip_bfloat16* __restrict__ gi)
{
    __shared__ alignas(16) float a_lds[32 * EDIM];
    int tid = threadIdx.x;
    int rowbase = blockIdx.x * 32;

    for (int i = tid; i < 32 * 75; i += 192) {   // 75 = 300/4
        int r = i / 75, e4 = i - r * 75;
        int row = rowbase + r;
        int tok = (row < nrows) ? toks[row] : 0;
        f4 v = *reinterpret_cast<const f4*>(emb + (size_t)tok * EDIM + e4 * 4);
        *reinterpret_cast<f4*>(a_lds + r * EDIM + e4 * 4) = v;
    }
    __syncthreads();

    int g0 = tid, g1 = tid + 192;
    float acc0[32], acc1[32];
#pragma unroll
    for (int r = 0; r < 32; r++) { acc0[r] = 0.f; acc1[r] = 0.f; }

    const float* w0p = w_ih + (size_t)g0 * EDIM;
    const float* w1p = w_ih + (size_t)g1 * EDIM;
    for (int e4 = 0; e4 < 75; ++e4) {
        f4 w0 = *reinterpret_cast<const f4*>(w0p + e4 * 4);
        f4 w1 = *reinterpret_cast<const f4*>(w1p + e4 * 4);
#pragma unroll
        for (int r = 0; r < 32; r++) {
            f4 a = *reinterpret_cast<const f4*>(a_lds + r * EDIM + e4 * 4);
            acc0[r] += a.x * w0.x + a.y * w0.y + a.z * w0.z + a.w * w0.w;
            acc1[r] += a.x * w1.x + a.y * w1.y + a.z * w1.z + a.w * w1.w;
        }
    }
    float bb0 = b_ih[g0], bb1 = b_ih[g1];
    for (int r = 0; r < 32; r++) {
        int row = rowbase + r;
        if (row < nrows) {
            gi[(size_t)row * G3 + g0] = __float2bfloat16(acc0[r] + bb0);
            gi[(size_t)row * G3 + g1] = __float2bfloat16(acc1[r] + bb1);
        }
    }
}

// ---------------------------------------------------------------------------
// K1b: dense variant, K = 128 (episodic gi from sents)
// ---------------------------------------------------------------------------
__global__ __launch_bounds__(192) void k_gi_dense(
    const float* __restrict__ x, int nrows,
    const float* __restrict__ w_ih, const float* __restrict__ b_ih,
    __hip_bfloat16* __restrict__ gi)
{
    __shared__ alignas(16) float a_lds[32 * HDIM];
    int tid = threadIdx.x;
    int rowbase = blockIdx.x * 32;

    for (int i = tid; i < 32 * 32; i += 192) {   // 32 = 128/4
        int r = i >> 5, e4 = i & 31;
        int row = rowbase + r;
        f4 v;
        if (row < nrows) v = *reinterpret_cast<const f4*>(x + (size_t)row * HDIM + e4 * 4);
        else { v.x = v.y = v.z = v.w = 0.f; }
        *reinterpret_cast<f4*>(a_lds + r * HDIM + e4 * 4) = v;
    }
    __syncthreads();

    int g0 = tid, g1 = tid + 192;
    float acc0[32], acc1[32];
#pragma unroll
    for (int r = 0; r < 32; r++) { acc0[r] = 0.f; acc1[r] = 0.f; }

    const float* w0p = w_ih + (size_t)g0 * HDIM;
    const float* w1p = w_ih + (size_t)g1 * HDIM;
    for (int e4 = 0; e4 < 32; ++e4) {
        f4 w0 = *reinterpret_cast<const f4*>(w0p + e4 * 4);
        f4 w1 = *reinterpret_cast<const f4*>(w1p + e4 * 4);
#pragma unroll
        for (int r = 0; r < 32; r++) {
            f4 a = *reinterpret_cast<const f4*>(a_lds + r * HDIM + e4 * 4);
            acc0[r] += a.x * w0.x + a.y * w0.y + a.z * w0.z + a.w * w0.w;
            acc1[r] += a.x * w1.x + a.y * w1.y + a.z * w1.z + a.w * w1.w;
        }
    }
    float bb0 = b_ih[g0], bb1 = b_ih[g1];
    for (int r = 0; r < 32; r++) {
        int row = rowbase + r;
        if (row < nrows) {
            gi[(size_t)row * G3 + g0] = __float2bfloat16(acc0[r] + bb0);
            gi[(size_t)row * G3 + g1] = __float2bfloat16(acc1[r] + bb1);
        }
    }
}

// ---------------------------------------------------------------------------
// K2: MFMA-batched GRU scan, swapped operands. 4 WGs x 16 batches, 512 thr.
// gh(384x16) = W(384x128) @ h^T(128x16): A=W frags in VGPRs (48, pinned),
// B=h frags from XOR-swizzled double-buffered LDS. Lane (w,l): batch=l&15,
// gates j0..j0+3 with j0=16w+4(l>>4) -> gi loads 3xb64, h-write 1xb64.
// One raw barrier per step (no vmcnt drain): t+1 gi prefetch stays in
// flight across it; lgkmcnt(0) guards the LDS hand-off.
// ---------------------------------------------------------------------------
template <int MODE>
__global__ __launch_bounds__(512, 2) void k_scan(
    const __hip_bfloat16* __restrict__ gi,   // [BATCH][T][384]
    int T,
    const float* __restrict__ w_hh, const float* __restrict__ b_hh,
    const int* __restrict__ mask,            // MODE 0
    float* __restrict__ sents,               // MODE 0
    const int* __restrict__ qtoks,           // MODE 1
    float* __restrict__ qv_out,              // MODE 1 (d_out)
    float* __restrict__ q_ws,                // MODE 1
    const float* __restrict__ gates,         // MODE 2
    float* __restrict__ h_out,               // MODE 2 (mem ws)
    float* __restrict__ ep_out)              // MODE 2 (d_out, nullable)
{
    __shared__ alignas(16) unsigned char h_raw[2 * WGB * 256];  // 2 x 4KB bufs

    const int tid = threadIdx.x;
    const int w   = tid >> 6;        // wave 0..7
    const int l   = tid & 63;
    const int col = l & 15;          // batch index within group; A-row m
    const int kg  = l >> 4;          // k-group 0..3
    const int b0  = blockIdx.x * WGB;
    const int bb  = b0 + col;        // this lane's batch
    const int j0  = 16 * w + 4 * kg; // first of this lane's 4 gate rows

    // ---- A fragments (weights), identical data layout to r9 (verified) ----
    const float* wr = w_hh + (size_t)(16 * w + col) * HDIM + kg * 8;
    const float* wz = w_hh + (size_t)(128 + 16 * w + col) * HDIM + kg * 8;
    const float* wn = w_hh + (size_t)(256 + 16 * w + col) * HDIM + kg * 8;
    bf16x8 Ar0 = packrow8(wr +  0), Ar1 = packrow8(wr + 32),
           Ar2 = packrow8(wr + 64), Ar3 = packrow8(wr + 96);
    bf16x8 Az0 = packrow8(wz +  0), Az1 = packrow8(wz + 32),
           Az2 = packrow8(wz + 64), Az3 = packrow8(wz + 96);
    bf16x8 An0 = packrow8(wn +  0), An1 = packrow8(wn + 32),
           An2 = packrow8(wn + 64), An3 = packrow8(wn + 96);
    asm volatile("" : "+v"(Ar0), "+v"(Ar1), "+v"(Ar2), "+v"(Ar3));
    asm volatile("" : "+v"(Az0), "+v"(Az1), "+v"(Az2), "+v"(Az3));
    asm volatile("" : "+v"(An0), "+v"(An1), "+v"(An2), "+v"(An3));

    // biases for this lane's 4 gate rows
    f4 br4 = *reinterpret_cast<const f4*>(b_hh + j0);
    f4 bz4 = *reinterpret_cast<const f4*>(b_hh + 128 + j0);
    f4 bn4 = *reinterpret_cast<const f4*>(b_hh + 256 + j0);

    // ---- XOR-swizzled LDS offsets (16B-block XOR keyed by batch row) ----
    int rdoff[4];
#pragma unroll
    for (int kk = 0; kk < 4; kk++)
        rdoff[kk] = col * 256 + (((kk * 4 + kg) ^ (col & 7)) << 4);
    const int wroff = col * 256 + ((((w << 1) | (kg >> 1)) ^ (col & 7)) << 4)
                      + ((kg & 1) << 3);

    // zero buffer 0
    for (int i = tid; i < WGB * 256 / 4; i += 512)
        reinterpret_cast<unsigned*>(h_raw)[i] = 0u;

    int qi = QLEN - 1;
    if (MODE == 1) {
        for (int t2 = 0; t2 < QLEN - 1; t2++)
            if (qtoks[bb * QLEN + t2 + 1] == 0) { qi = t2; break; }
    }
    int scnt = 0;

    // prefetch gi(t=0) (+mask/gate)
    const __hip_bfloat16* gib = gi + (size_t)bb * T * G3;
    ushort4 cr4, cz4, cn4;
    int cm = 0;
    float cw = 0.f;
    {
        const unsigned short* gp = reinterpret_cast<const unsigned short*>(gib);
        cr4 = *reinterpret_cast<const ushort4*>(gp + j0);
        cz4 = *reinterpret_cast<const ushort4*>(gp + 128 + j0);
        cn4 = *reinterpret_cast<const ushort4*>(gp + 256 + j0);
        if (MODE == 0) cm = mask[bb * LSTO];
        if (MODE == 2) cw = gates[bb * NSENT];
    }
    float hp[4] = {0.f, 0.f, 0.f, 0.f};
    __syncthreads();

    int rb = 0;   // read-buffer byte base (0 / 4096)
    for (int t = 0; t < T; ++t) {
        // ---- B-fragments: h_{t-1}[batch=col][k] from swizzled LDS ----
        bf16x8 H0 = *reinterpret_cast<const bf16x8*>(h_raw + rb + rdoff[0]);
        bf16x8 H1 = *reinterpret_cast<const bf16x8*>(h_raw + rb + rdoff[1]);
        bf16x8 H2 = *reinterpret_cast<const bf16x8*>(h_raw + rb + rdoff[2]);
        bf16x8 H3 = *reinterpret_cast<const bf16x8*>(h_raw + rb + rdoff[3]);

        // ---- issue gi prefetch for t+1 (stays in flight across barrier) ----
        int tn = (t + 1 < T) ? t + 1 : t;
        ushort4 nr4, nz4, nn4;
        int nm = 0;
        float nw = 0.f;
        {
            const unsigned short* gp =
                reinterpret_cast<const unsigned short*>(gib + (size_t)tn * G3);
            nr4 = *reinterpret_cast<const ushort4*>(gp + j0);
            nz4 = *reinterpret_cast<const ushort4*>(gp + 128 + j0);
            nn4 = *reinterpret_cast<const ushort4*>(gp + 256 + j0);
            if (MODE == 0) nm = mask[bb * LSTO + tn];
            if (MODE == 2) nw = gates[bb * NSENT + tn];
        }

        // ---- MFMA: D[gate][batch] = W @ h^T, 3 gate-tiles x K=128 ----
        f32x4 accr = {br4.x, br4.y, br4.z, br4.w};
        f32x4 accz = {bz4.x, bz4.y, bz4.z, bz4.w};
        f32x4 accn = {bn4.x, bn4.y, bn4.z, bn4.w};
        accr = __builtin_amdgcn_mfma_f32_16x16x32_bf16(Ar0, H0, accr, 0, 0, 0);
        accz = __builtin_amdgcn_mfma_f32_16x16x32_bf16(Az0, H0, accz, 0, 0, 0);
        accn = __builtin_amdgcn_mfma_f32_16x16x32_bf16(An0, H0, accn, 0, 0, 0);
        accr = __builtin_amdgcn_mfma_f32_16x16x32_bf16(Ar1, H1, accr, 0, 0, 0);
        accz = __builtin_amdgcn_mfma_f32_16x16x32_bf16(Az1, H1, accz, 0, 0, 0);
        accn = __builtin_amdgcn_mfma_f32_16x16x32_bf16(An1, H1, accn, 0, 0, 0);
        accr = __builtin_amdgcn_mfma_f32_16x16x32_bf16(Ar2, H2, accr, 0, 0, 0);
        accz = __builtin_amdgcn_mfma_f32_16x16x32_bf16(Az2, H2, accz, 0, 0, 0);
        accn = __builtin_amdgcn_mfma_f32_16x16x32_bf16(An2, H2, accn, 0, 0, 0);
        accr = __builtin_amdgcn_mfma_f32_16x16x32_bf16(Ar3, H3, accr, 0, 0, 0);
        accz = __builtin_amdgcn_mfma_f32_16x16x32_bf16(Az3, H3, accz, 0, 0, 0);
        accn = __builtin_amdgcn_mfma_f32_16x16x32_bf16(An3, H3, accn, 0, 0, 0);

        // ---- pointwise GRU: 4 gates of one batch, fully in-register ----
        {
            float r0 = sigmf(bf2f(cr4.x) + accr[0]);
            float r1 = sigmf(bf2f(cr4.y) + accr[1]);
            float r2 = sigmf(bf2f(cr4.z) + accr[2]);
            float r3 = sigmf(bf2f(cr4.w) + accr[3]);
            float z0 = sigmf(bf2f(cz4.x) + accz[0]);
            float z1 = sigmf(bf2f(cz4.y) + accz[1]);
            float z2 = sigmf(bf2f(cz4.z) + accz[2]);
            float z3 = sigmf(bf2f(cz4.w) + accz[3]);
            float n0 = tanhfast(bf2f(cn4.x) + r0 * accn[0]);
            float n1 = tanhfast(bf2f(cn4.y) + r1 * accn[1]);
            float n2 = tanhfast(bf2f(cn4.z) + r2 * accn[2]);
            float n3 = tanhfast(bf2f(cn4.w) + r3 * accn[3]);
            float h0 = (1.f - z0) * n0 + z0 * hp[0];
            float h1 = (1.f - z1) * n1 + z1 * hp[1];
            float h2 = (1.f - z2) * n2 + z2 * hp[2];
            float h3 = (1.f - z3) * n3 + z3 * hp[3];
            if (MODE == 2) {
                h0 = cw * h0 + (1.f - cw) * hp[0];
                h1 = cw * h1 + (1.f - cw) * hp[1];
                h2 = cw * h2 + (1.f - cw) * hp[2];
                h3 = cw * h3 + (1.f - cw) * hp[3];
            }
            hp[0] = h0; hp[1] = h1; hp[2] = h2; hp[3] = h3;
        }

        // ---- write h_t into the OTHER buffer (no WAR vs readers) ----
        uint2 hw;
        hw.x = pack2bf(hp[0], hp[1]);
        hw.y = pack2bf(hp[2], hp[3]);
        *reinterpret_cast<uint2*>(h_raw + (rb ^ 4096) + wroff) = hw;

        // ---- conditional global outputs ----
        if (MODE == 0) {
            if (cm) {
                if (scnt < NSENT) {
                    float4 v = make_float4(hp[0], hp[1], hp[2], hp[3]);
                    *reinterpret_cast<float4*>(
                        sents + ((size_t)bb * NSENT + scnt) * HDIM + j0) = v;
                }
                scnt++;
            }
        }
        if (MODE == 1 && t == qi) {
            float4 v = make_float4(hp[0], hp[1], hp[2], hp[3]);
            *reinterpret_cast<float4*>(qv_out + bb * HDIM + j0) = v;
            *reinterpret_cast<float4*>(q_ws + bb * HDIM + j0) = v;
        }
        if (MODE == 2 && t == T - 1) {
            float4 v = make_float4(hp[0], hp[1], hp[2], hp[3]);
            *reinterpret_cast<float4*>(h_out + bb * HDIM + j0) = v;
            if (ep_out)
                *reinterpret_cast<float4*>(ep_out + bb * HDIM + j0) = v;
        }

        lgkm0();              // ds_write visible
        barrier_nodrain();    // single barrier per step; vmcnt stays in flight
        rb ^= 4096;

        cr4 = nr4; cz4 = nz4; cn4 = nn4;
        if (MODE == 0) cm = nm;
        if (MODE == 2) cw = nw;
    }
}

// ---------------------------------------------------------------------------
// K3: attention gates.  WG per batch, 128 threads = (16 t) x (8 segments).
// ---------------------------------------------------------------------------
__global__ __launch_bounds__(128) void k_gates(
    const float* __restrict__ sents, const float* __restrict__ q_ws,
    const float* __restrict__ mem, const float* __restrict__ gate_w,
    const float* __restrict__ gate_b,
    float* __restrict__ gates_ws, float* __restrict__ gout)
{
    int b = blockIdx.x, tid = threadIdx.x;
    int t = tid >> 3, s = tid & 7;
    float p = 0.f;
    const float* sv = sents + ((size_t)b * NSENT + t) * HDIM;
    for (int jj = 0; jj < 16; jj++) {
        int j = s * 16 + jj;
        float S = sv[j], Q = q_ws[b * HDIM + j], M = mem[b * HDIM + j];
        float dq = S - Q, dm = S - M;
        p += (S * Q) * gate_w[j] + (S * M) * gate_w[HDIM + j] +
             (dq * dq) * gate_w[2 * HDIM + j] + (dm * dm) * gate_w[3 * HDIM + j];
    }
    __shared__ float red[16][8];
    red[t][s] = p;
    __syncthreads();
    if (s == 0) {
        float sum = 0.f;
        for (int k = 0; k < 8; k++) sum += red[t][k];
        float gt = sigmf(sum + gate_b[0]);
        gates_ws[b * NSENT + t] = gt;
        if (gout) gout[b * NSENT + t] = gt;
    }
}

// ---------------------------------------------------------------------------
extern "C" void kernel_launch(void* const* d_in, const int* in_sizes, int n_in,
                              void* d_out, int out_size, void* d_ws, size_t ws_size,
                              hipStream_t stream)
{
    const int*   x_sto    = (const int*)d_in[0];
    const int*   x_mask   = (const int*)d_in[1];
    const int*   x_q      = (const int*)d_in[2];
    const float* emb      = (const float*)d_in[4];
    const float* enc_w_ih = (const float*)d_in[5];
    const float* enc_w_hh = (const float*)d_in[6];
    const float* enc_b_ih = (const float*)d_in[7];
    const float* enc_b_hh = (const float*)d_in[8];
    const float* gate_w   = (const float*)d_in[9];
    const float* gate_b   = (const float*)d_in[10];
    const float* ep_w_ih  = (const float*)d_in[11];
    const float* ep_w_hh  = (const float*)d_in[12];
    const float* ep_b_ih  = (const float*)d_in[13];
    const float* ep_b_hh  = (const float*)d_in[14];

    float* out_q  = (float*)d_out;                       // (64,128)
    float* out_ep = (float*)d_out + BATCH * HDIM;        // (1,64,128)
    float* out_g  = (float*)d_out + 2 * BATCH * HDIM;    // (64,16)

    char* ws = (char*)d_ws;
    size_t off = 0;
    auto alloc = [&](size_t bytes) {
        void* p = ws + off;
        off += (bytes + 255) & ~(size_t)255;
        return p;
    };
    __hip_bfloat16* gi_sto = (__hip_bfloat16*)alloc((size_t)BATCH * LSTO * G3 * 2);
    __hip_bfloat16* gi_q   = (__hip_bfloat16*)alloc((size_t)BATCH * QLEN * G3 * 2);
    __hip_bfloat16* gi_ep  = (__hip_bfloat16*)alloc((size_t)BATCH * NSENT * G3 * 2);
    float* sents    = (float*)alloc((size_t)BATCH * NSENT * HDIM * 4);
    float* q_ws     = (float*)alloc((size_t)BATCH * HDIM * 4);
    float* mem      = (float*)alloc((size_t)BATCH * HDIM * 4);
    float* gates_ws = (float*)alloc((size_t)BATCH * NSENT * 4);
    (void)ws_size; (void)in_sizes; (void)n_in; (void)out_size;

    // Phase A: input-projection GEMMs (gather + matmul), bf16 output
    k_gi_gather<<<(BATCH * LSTO) / 32, 192, 0, stream>>>(
        x_sto, BATCH * LSTO, emb, enc_w_ih, enc_b_ih, gi_sto);
    k_gi_gather<<<(BATCH * QLEN) / 32, 192, 0, stream>>>(
        x_q, BATCH * QLEN, emb, enc_w_ih, enc_b_ih, gi_q);

    // Phase B: story scan (writes sents), question scan (writes q_vecs)
    k_scan<0><<<BATCH / WGB, 512, 0, stream>>>(
        gi_sto, LSTO, enc_w_hh, enc_b_hh,
        x_mask, sents, nullptr, nullptr, nullptr, nullptr, nullptr, nullptr);
    k_scan<1><<<BATCH / WGB, 512, 0, stream>>>(
        gi_q, QLEN, enc_w_hh, enc_b_hh,
        nullptr, nullptr, x_q, out_q, q_ws, nullptr, nullptr, nullptr);

    // Phase C: episodic memory, 3 iterations
    k_gi_dense<<<(BATCH * NSENT) / 32, 192, 0, stream>>>(
        sents, BATCH * NSENT, ep_w_ih, ep_b_ih, gi_ep);

    for (int it = 0; it < 3; ++it) {
        const float* msrc = (it == 0) ? q_ws : mem;
        k_gates<<<BATCH, 128, 0, stream>>>(
            sents, q_ws, msrc, gate_w, gate_b, gates_ws,
            (it == 2) ? out_g : nullptr);
        k_scan<2><<<BATCH / WGB, 512, 0, stream>>>(
            gi_ep, NSENT, ep_w_hh, ep_b_hh,
            nullptr, nullptr, nullptr, nullptr, nullptr,
            gates_ws, mem, (it == 2) ? out_ep : nullptr);
    }
}

// Round 12
// 1784.065 us; speedup vs baseline: 1.3336x; 1.0085x over previous
//
#include <hip/hip_runtime.h>
#include <hip/hip_bf16.h>

#define HDIM 128
#define G3 384          // 3*H
#define EDIM 300
#define BATCH 64
#define LSTO 1024
#define QLEN 32
#define NSENT 16
#define WGB 16          // batches per scan workgroup
#define HROW 272        // padded h row: 17 x 16B -> conflict-free b128
#define HBUF (WGB * HROW)

typedef float4 f4;
typedef __attribute__((ext_vector_type(8))) short bf16x8;
typedef __attribute__((ext_vector_type(4))) float f32x4;

__device__ __forceinline__ float sigmf(float x) { return 1.0f / (1.0f + __expf(-x)); }
__device__ __forceinline__ float tanhfast(float x) {
    float e = __expf(-2.0f * x);
    return (1.0f - e) / (1.0f + e);
}
__device__ __forceinline__ float bf2f(unsigned short u) {
    return __uint_as_float(((unsigned)u) << 16);
}
__device__ __forceinline__ unsigned short f2bf_u(float f) {
    union { __hip_bfloat16 b; unsigned short s; } u;
    u.b = __float2bfloat16(f);
    return u.s;
}
__device__ __forceinline__ short f2bf_s(float f) {
    union { __hip_bfloat16 b; short s; } u;
    u.b = __float2bfloat16(f);
    return u.s;
}
__device__ __forceinline__ bf16x8 packrow8(const float* p) {
    bf16x8 v;
#pragma unroll
    for (int i = 0; i < 8; i++) v[i] = f2bf_s(p[i]);
    return v;
}
__device__ __forceinline__ unsigned pack2bf(float a, float b) {
    return ((unsigned)f2bf_u(b) << 16) | (unsigned)f2bf_u(a);
}
__device__ __forceinline__ void barrier_nodrain() {
    asm volatile("" ::: "memory");
    __builtin_amdgcn_s_barrier();
    asm volatile("" ::: "memory");
}
__device__ __forceinline__ void lgkm0() {
    asm volatile("s_waitcnt lgkmcnt(0)" ::: "memory");
    __builtin_amdgcn_sched_barrier(0);
}

// ---------------------------------------------------------------------------
// K1: gi[row][g] = b_ih[g] + emb[tok[row]] . w_ih[g]   (K = 300), bf16 out
// Rows processed in two 16-row passes so acc fits in 32 VGPRs (no spill).
// ---------------------------------------------------------------------------
__global__ __launch_bounds__(192) void k_gi_gather(
    const int* __restrict__ toks, int nrows,
    const float* __restrict__ emb,
    const float* __restrict__ w_ih, const float* __restrict__ b_ih,
    __hip_bfloat16* __restrict__ gi)
{
    __shared__ alignas(16) float a_lds[32 * EDIM];
    int tid = threadIdx.x;
    int rowbase = blockIdx.x * 32;

    for (int i = tid; i < 32 * 75; i += 192) {   // 75 = 300/4
        int r = i / 75, e4 = i - r * 75;
        int row = rowbase + r;
        int tok = (row < nrows) ? toks[row] : 0;
        f4 v = *reinterpret_cast<const f4*>(emb + (size_t)tok * EDIM + e4 * 4);
        *reinterpret_cast<f4*>(a_lds + r * EDIM + e4 * 4) = v;
    }
    __syncthreads();

    int g0 = tid, g1 = tid + 192;
    const float* w0p = w_ih + (size_t)g0 * EDIM;
    const float* w1p = w_ih + (size_t)g1 * EDIM;
    float bb0 = b_ih[g0], bb1 = b_ih[g1];

#pragma unroll
    for (int half = 0; half < 2; half++) {
        float acc0[16], acc1[16];
#pragma unroll
        for (int r = 0; r < 16; r++) { acc0[r] = 0.f; acc1[r] = 0.f; }

        for (int e4 = 0; e4 < 75; ++e4) {
            f4 w0 = *reinterpret_cast<const f4*>(w0p + e4 * 4);
            f4 w1 = *reinterpret_cast<const f4*>(w1p + e4 * 4);
#pragma unroll
            for (int r = 0; r < 16; r++) {
                f4 a = *reinterpret_cast<const f4*>(
                    a_lds + (half * 16 + r) * EDIM + e4 * 4);
                acc0[r] += a.x * w0.x + a.y * w0.y + a.z * w0.z + a.w * w0.w;
                acc1[r] += a.x * w1.x + a.y * w1.y + a.z * w1.z + a.w * w1.w;
            }
        }
#pragma unroll
        for (int r = 0; r < 16; r++) {
            int row = rowbase + half * 16 + r;
            if (row < nrows) {
                gi[(size_t)row * G3 + g0] = __float2bfloat16(acc0[r] + bb0);
                gi[(size_t)row * G3 + g1] = __float2bfloat16(acc1[r] + bb1);
            }
        }
    }
}

// ---------------------------------------------------------------------------
// K1b: dense variant, K = 128 (episodic gi from sents)
// ---------------------------------------------------------------------------
__global__ __launch_bounds__(192) void k_gi_dense(
    const float* __restrict__ x, int nrows,
    const float* __restrict__ w_ih, const float* __restrict__ b_ih,
    __hip_bfloat16* __restrict__ gi)
{
    __shared__ alignas(16) float a_lds[32 * HDIM];
    int tid = threadIdx.x;
    int rowbase = blockIdx.x * 32;

    for (int i = tid; i < 32 * 32; i += 192) {   // 32 = 128/4
        int r = i >> 5, e4 = i & 31;
        int row = rowbase + r;
        f4 v;
        if (row < nrows) v = *reinterpret_cast<const f4*>(x + (size_t)row * HDIM + e4 * 4);
        else { v.x = v.y = v.z = v.w = 0.f; }
        *reinterpret_cast<f4*>(a_lds + r * HDIM + e4 * 4) = v;
    }
    __syncthreads();

    int g0 = tid, g1 = tid + 192;
    const float* w0p = w_ih + (size_t)g0 * HDIM;
    const float* w1p = w_ih + (size_t)g1 * HDIM;
    float bb0 = b_ih[g0], bb1 = b_ih[g1];

#pragma unroll
    for (int half = 0; half < 2; half++) {
        float acc0[16], acc1[16];
#pragma unroll
        for (int r = 0; r < 16; r++) { acc0[r] = 0.f; acc1[r] = 0.f; }

        for (int e4 = 0; e4 < 32; ++e4) {
            f4 w0 = *reinterpret_cast<const f4*>(w0p + e4 * 4);
            f4 w1 = *reinterpret_cast<const f4*>(w1p + e4 * 4);
#pragma unroll
            for (int r = 0; r < 16; r++) {
                f4 a = *reinterpret_cast<const f4*>(
                    a_lds + (half * 16 + r) * HDIM + e4 * 4);
                acc0[r] += a.x * w0.x + a.y * w0.y + a.z * w0.z + a.w * w0.w;
                acc1[r] += a.x * w1.x + a.y * w1.y + a.z * w1.z + a.w * w1.w;
            }
        }
#pragma unroll
        for (int r = 0; r < 16; r++) {
            int row = rowbase + half * 16 + r;
            if (row < nrows) {
                gi[(size_t)row * G3 + g0] = __float2bfloat16(acc0[r] + bb0);
                gi[(size_t)row * G3 + g1] = __float2bfloat16(acc1[r] + bb1);
            }
        }
    }
}

// ---------------------------------------------------------------------------
// K2: MFMA-batched GRU scan, swapped operands, unroll-2, padded LDS.
// 4 WGs x 16 batches, 512 thr. gh(384x16) = W(384x128) @ h^T(128x16).
// A=W frags in VGPRs (pinned). h rows padded to 272B (bank-optimal).
// Unroll-2 with alternating gi register sets A/B: no copies, so the
// prefetch vmcnt wait lands in the NEXT step after barrier+ds+MFMA.
// ---------------------------------------------------------------------------
#define SCAN_BODY(TT, TPF, RB, WB, C, P)                                       \
  {                                                                            \
    const int t_ = (TT);                                                       \
    bf16x8 H0 = *reinterpret_cast<const bf16x8*>(h_raw + (RB) + rd0);          \
    bf16x8 H1 = *reinterpret_cast<const bf16x8*>(h_raw + (RB) + rd1);          \
    bf16x8 H2 = *reinterpret_cast<const bf16x8*>(h_raw + (RB) + rd2);          \
    bf16x8 H3 = *reinterpret_cast<const bf16x8*>(h_raw + (RB) + rd3);          \
    {                                                                          \
      const int tp_ = (TPF);                                                   \
      const unsigned short* gp =                                               \
          reinterpret_cast<const unsigned short*>(gib + (size_t)tp_ * G3);     \
      cr##P = *reinterpret_cast<const ushort4*>(gp + j0);                      \
      cz##P = *reinterpret_cast<const ushort4*>(gp + 128 + j0);                \
      cn##P = *reinterpret_cast<const ushort4*>(gp + 256 + j0);                \
      if (MODE == 0) cm##P = mask[bb * LSTO + tp_];                            \
      if (MODE == 2) cw##P = gates[bb * NSENT + tp_];                          \
    }                                                                          \
    f32x4 accr = {br4.x, br4.y, br4.z, br4.w};                                 \
    f32x4 accz = {bz4.x, bz4.y, bz4.z, bz4.w};                                 \
    f32x4 accn = {bn4.x, bn4.y, bn4.z, bn4.w};                                 \
    accr = __builtin_amdgcn_mfma_f32_16x16x32_bf16(Ar0, H0, accr, 0, 0, 0);    \
    accz = __builtin_amdgcn_mfma_f32_16x16x32_bf16(Az0, H0, accz, 0, 0, 0);    \
    accn = __builtin_amdgcn_mfma_f32_16x16x32_bf16(An0, H0, accn, 0, 0, 0);    \
    accr = __builtin_amdgcn_mfma_f32_16x16x32_bf16(Ar1, H1, accr, 0, 0, 0);    \
    accz = __builtin_amdgcn_mfma_f32_16x16x32_bf16(Az1, H1, accz, 0, 0, 0);    \
    accn = __builtin_amdgcn_mfma_f32_16x16x32_bf16(An1, H1, accn, 0, 0, 0);    \
    accr = __builtin_amdgcn_mfma_f32_16x16x32_bf16(Ar2, H2, accr, 0, 0, 0);    \
    accz = __builtin_amdgcn_mfma_f32_16x16x32_bf16(Az2, H2, accz, 0, 0, 0);    \
    accn = __builtin_amdgcn_mfma_f32_16x16x32_bf16(An2, H2, accn, 0, 0, 0);    \
    accr = __builtin_amdgcn_mfma_f32_16x16x32_bf16(Ar3, H3, accr, 0, 0, 0);    \
    accz = __builtin_amdgcn_mfma_f32_16x16x32_bf16(Az3, H3, accz, 0, 0, 0);    \
    accn = __builtin_amdgcn_mfma_f32_16x16x32_bf16(An3, H3, accn, 0, 0, 0);    \
    {                                                                          \
      float r0 = sigmf(bf2f(cr##C.x) + accr[0]);                               \
      float r1 = sigmf(bf2f(cr##C.y) + accr[1]);                               \
      float r2 = sigmf(bf2f(cr##C.z) + accr[2]);                               \
      float r3 = sigmf(bf2f(cr##C.w) + accr[3]);                               \
      float z0 = sigmf(bf2f(cz##C.x) + accz[0]);                               \
      float z1 = sigmf(bf2f(cz##C.y) + accz[1]);                               \
      float z2 = sigmf(bf2f(cz##C.z) + accz[2]);                               \
      float z3 = sigmf(bf2f(cz##C.w) + accz[3]);                               \
      float n0 = tanhfast(bf2f(cn##C.x) + r0 * accn[0]);                       \
      float n1 = tanhfast(bf2f(cn##C.y) + r1 * accn[1]);                       \
      float n2 = tanhfast(bf2f(cn##C.z) + r2 * accn[2]);                       \
      float n3 = tanhfast(bf2f(cn##C.w) + r3 * accn[3]);                       \
      float h0 = (1.f - z0) * n0 + z0 * hp0;                                   \
      float h1 = (1.f - z1) * n1 + z1 * hp1;                                   \
      float h2 = (1.f - z2) * n2 + z2 * hp2;                                   \
      float h3 = (1.f - z3) * n3 + z3 * hp3;                                   \
      if (MODE == 2) {                                                         \
        h0 = cw##C * h0 + (1.f - cw##C) * hp0;                                 \
        h1 = cw##C * h1 + (1.f - cw##C) * hp1;                                 \
        h2 = cw##C * h2 + (1.f - cw##C) * hp2;                                 \
        h3 = cw##C * h3 + (1.f - cw##C) * hp3;                                 \
      }                                                                        \
      hp0 = h0; hp1 = h1; hp2 = h2; hp3 = h3;                                  \
    }                                                                          \
    {                                                                          \
      uint2 hw_;                                                               \
      hw_.x = pack2bf(hp0, hp1);                                               \
      hw_.y = pack2bf(hp2, hp3);                                               \
      *reinterpret_cast<uint2*>(h_raw + (WB) + wroff) = hw_;                   \
    }                                                                          \
    if (MODE == 0) {                                                           \
      if (cm##C) {                                                             \
        if (scnt < NSENT) {                                                    \
          float4 v_ = make_float4(hp0, hp1, hp2, hp3);                         \
          *reinterpret_cast<float4*>(                                          \
              sents + ((size_t)bb * NSENT + scnt) * HDIM + j0) = v_;           \
        }                                                                      \
        scnt++;                                                                \
      }                                                                        \
    }                                                                          \
    if (MODE == 1 && t_ == qi) {                                               \
      float4 v_ = make_float4(hp0, hp1, hp2, hp3);                             \
      *reinterpret_cast<float4*>(qv_out + bb * HDIM + j0) = v_;                \
      *reinterpret_cast<float4*>(q_ws + bb * HDIM + j0) = v_;                  \
    }                                                                          \
    if (MODE == 2 && t_ == T - 1) {                                            \
      float4 v_ = make_float4(hp0, hp1, hp2, hp3);                             \
      *reinterpret_cast<float4*>(h_out + bb * HDIM + j0) = v_;                 \
      if (ep_out)                                                              \
        *reinterpret_cast<float4*>(ep_out + bb * HDIM + j0) = v_;              \
    }                                                                          \
    lgkm0();                                                                   \
    barrier_nodrain();                                                         \
  }

template <int MODE>
__global__ __launch_bounds__(512, 2) void k_scan(
    const __hip_bfloat16* __restrict__ gi,   // [BATCH][T][384]
    int T,
    const float* __restrict__ w_hh, const float* __restrict__ b_hh,
    const int* __restrict__ mask,            // MODE 0
    float* __restrict__ sents,               // MODE 0
    const int* __restrict__ qtoks,           // MODE 1
    float* __restrict__ qv_out,              // MODE 1 (d_out)
    float* __restrict__ q_ws,                // MODE 1
    const float* __restrict__ gates,         // MODE 2
    float* __restrict__ h_out,               // MODE 2 (mem ws)
    float* __restrict__ ep_out)              // MODE 2 (d_out, nullable)
{
    __shared__ alignas(16) unsigned char h_raw[2 * HBUF];

    const int tid = threadIdx.x;
    const int w   = tid >> 6;        // wave 0..7
    const int l   = tid & 63;
    const int col = l & 15;          // batch (B-frag col / A-frag row-in-slice)
    const int kg  = l >> 4;          // k-group 0..3
    const int b0  = blockIdx.x * WGB;
    const int bb  = b0 + col;        // this lane's batch
    const int j0  = 16 * w + 4 * kg; // first of this lane's 4 gate rows

    // ---- A fragments (weights): 12 x bf16x8, pinned ----
    const float* wr = w_hh + (size_t)(16 * w + col) * HDIM + kg * 8;
    const float* wz = w_hh + (size_t)(128 + 16 * w + col) * HDIM + kg * 8;
    const float* wn = w_hh + (size_t)(256 + 16 * w + col) * HDIM + kg * 8;
    bf16x8 Ar0 = packrow8(wr +  0), Ar1 = packrow8(wr + 32),
           Ar2 = packrow8(wr + 64), Ar3 = packrow8(wr + 96);
    bf16x8 Az0 = packrow8(wz +  0), Az1 = packrow8(wz + 32),
           Az2 = packrow8(wz + 64), Az3 = packrow8(wz + 96);
    bf16x8 An0 = packrow8(wn +  0), An1 = packrow8(wn + 32),
           An2 = packrow8(wn + 64), An3 = packrow8(wn + 96);
    asm volatile("" : "+v"(Ar0), "+v"(Ar1), "+v"(Ar2), "+v"(Ar3));
    asm volatile("" : "+v"(Az0), "+v"(Az1), "+v"(Az2), "+v"(Az3));
    asm volatile("" : "+v"(An0), "+v"(An1), "+v"(An2), "+v"(An3));

    f4 br4 = *reinterpret_cast<const f4*>(b_hh + j0);
    f4 bz4 = *reinterpret_cast<const f4*>(b_hh + 128 + j0);
    f4 bn4 = *reinterpret_cast<const f4*>(b_hh + 256 + j0);

    // ---- padded-row LDS offsets (bank-optimal, no swizzle) ----
    const int rd0 = col * HROW + 0 * 64 + kg * 16;
    const int rd1 = col * HROW + 1 * 64 + kg * 16;
    const int rd2 = col * HROW + 2 * 64 + kg * 16;
    const int rd3 = col * HROW + 3 * 64 + kg * 16;
    const int wroff = col * HROW + j0 * 2;

    // zero both buffers
    for (int i = tid; i < 2 * HBUF / 4; i += 512)
        reinterpret_cast<unsigned*>(h_raw)[i] = 0u;

    int qi = QLEN - 1;
    if (MODE == 1) {
        for (int t2 = 0; t2 < QLEN - 1; t2++)
            if (qtoks[bb * QLEN + t2 + 1] == 0) { qi = t2; break; }
    }
    int scnt = 0;

    // preload gi(t=0) into set A
    const __hip_bfloat16* gib = gi + (size_t)bb * T * G3;
    ushort4 crA, czA, cnA, crB, czB, cnB;
    int cmA = 0, cmB = 0;
    float cwA = 0.f, cwB = 0.f;
    {
        const unsigned short* gp = reinterpret_cast<const unsigned short*>(gib);
        crA = *reinterpret_cast<const ushort4*>(gp + j0);
        czA = *reinterpret_cast<const ushort4*>(gp + 128 + j0);
        cnA = *reinterpret_cast<const ushort4*>(gp + 256 + j0);
        if (MODE == 0) cmA = mask[bb * LSTO];
        if (MODE == 2) cwA = gates[bb * NSENT];
    }
    float hp0 = 0.f, hp1 = 0.f, hp2 = 0.f, hp3 = 0.f;
    __syncthreads();

    // T is even for all modes (1024 / 32 / 16)
    for (int t = 0; t < T; t += 2) {
        SCAN_BODY(t,     t + 1,                     0,    HBUF, A, B)
        SCAN_BODY(t + 1, (t + 2 < T ? t + 2 : t+1), HBUF, 0,    B, A)
    }
}

// ---------------------------------------------------------------------------
// K3: attention gates.  WG per batch, 128 threads = (16 t) x (8 segments).
// ---------------------------------------------------------------------------
__global__ __launch_bounds__(128) void k_gates(
    const float* __restrict__ sents, const float* __restrict__ q_ws,
    const float* __restrict__ mem, const float* __restrict__ gate_w,
    const float* __restrict__ gate_b,
    float* __restrict__ gates_ws, float* __restrict__ gout)
{
    int b = blockIdx.x, tid = threadIdx.x;
    int t = tid >> 3, s = tid & 7;
    float p = 0.f;
    const float* sv = sents + ((size_t)b * NSENT + t) * HDIM;
    for (int jj = 0; jj < 16; jj++) {
        int j = s * 16 + jj;
        float S = sv[j], Q = q_ws[b * HDIM + j], M = mem[b * HDIM + j];
        float dq = S - Q, dm = S - M;
        p += (S * Q) * gate_w[j] + (S * M) * gate_w[HDIM + j] +
             (dq * dq) * gate_w[2 * HDIM + j] + (dm * dm) * gate_w[3 * HDIM + j];
    }
    __shared__ float red[16][8];
    red[t][s] = p;
    __syncthreads();
    if (s == 0) {
        float sum = 0.f;
        for (int k = 0; k < 8; k++) sum += red[t][k];
        float gt = sigmf(sum + gate_b[0]);
        gates_ws[b * NSENT + t] = gt;
        if (gout) gout[b * NSENT + t] = gt;
    }
}

// ---------------------------------------------------------------------------
extern "C" void kernel_launch(void* const* d_in, const int* in_sizes, int n_in,
                              void* d_out, int out_size, void* d_ws, size_t ws_size,
                              hipStream_t stream)
{
    const int*   x_sto    = (const int*)d_in[0];
    const int*   x_mask   = (const int*)d_in[1];
    const int*   x_q      = (const int*)d_in[2];
    const float* emb      = (const float*)d_in[4];
    const float* enc_w_ih = (const float*)d_in[5];
    const float* enc_w_hh = (const float*)d_in[6];
    const float* enc_b_ih = (const float*)d_in[7];
    const float* enc_b_hh = (const float*)d_in[8];
    const float* gate_w   = (const float*)d_in[9];
    const float* gate_b   = (const float*)d_in[10];
    const float* ep_w_ih  = (const float*)d_in[11];
    const float* ep_w_hh  = (const float*)d_in[12];
    const float* ep_b_ih  = (const float*)d_in[13];
    const float* ep_b_hh  = (const float*)d_in[14];

    float* out_q  = (float*)d_out;                       // (64,128)
    float* out_ep = (float*)d_out + BATCH * HDIM;        // (1,64,128)
    float* out_g  = (float*)d_out + 2 * BATCH * HDIM;    // (64,16)

    char* ws = (char*)d_ws;
    size_t off = 0;
    auto alloc = [&](size_t bytes) {
        void* p = ws + off;
        off += (bytes + 255) & ~(size_t)255;
        return p;
    };
    __hip_bfloat16* gi_sto = (__hip_bfloat16*)alloc((size_t)BATCH * LSTO * G3 * 2);
    __hip_bfloat16* gi_q   = (__hip_bfloat16*)alloc((size_t)BATCH * QLEN * G3 * 2);
    __hip_bfloat16* gi_ep  = (__hip_bfloat16*)alloc((size_t)BATCH * NSENT * G3 * 2);
    float* sents    = (float*)alloc((size_t)BATCH * NSENT * HDIM * 4);
    float* q_ws     = (float*)alloc((size_t)BATCH * HDIM * 4);
    float* mem      = (float*)alloc((size_t)BATCH * HDIM * 4);
    float* gates_ws = (float*)alloc((size_t)BATCH * NSENT * 4);
    (void)ws_size; (void)in_sizes; (void)n_in; (void)out_size;

    // Phase A: input-projection GEMMs (gather + matmul), bf16 output
    k_gi_gather<<<(BATCH * LSTO) / 32, 192, 0, stream>>>(
        x_sto, BATCH * LSTO, emb, enc_w_ih, enc_b_ih, gi_sto);
    k_gi_gather<<<(BATCH * QLEN) / 32, 192, 0, stream>>>(
        x_q, BATCH * QLEN, emb, enc_w_ih, enc_b_ih, gi_q);

    // Phase B: story scan (writes sents), question scan (writes q_vecs)
    k_scan<0><<<BATCH / WGB, 512, 0, stream>>>(
        gi_sto, LSTO, enc_w_hh, enc_b_hh,
        x_mask, sents, nullptr, nullptr, nullptr, nullptr, nullptr, nullptr);
    k_scan<1><<<BATCH / WGB, 512, 0, stream>>>(
        gi_q, QLEN, enc_w_hh, enc_b_hh,
        nullptr, nullptr, x_q, out_q, q_ws, nullptr, nullptr, nullptr);

    // Phase C: episodic memory, 3 iterations
    k_gi_dense<<<(BATCH * NSENT) / 32, 192, 0, stream>>>(
        sents, BATCH * NSENT, ep_w_ih, ep_b_ih, gi_ep);

    for (int it = 0; it < 3; ++it) {
        const float* msrc = (it == 0) ? q_ws : mem;
        k_gates<<<BATCH, 128, 0, stream>>>(
            sents, q_ws, msrc, gate_w, gate_b, gates_ws,
            (it == 2) ? out_g : nullptr);
        k_scan<2><<<BATCH / WGB, 512, 0, stream>>>(
            gi_ep, NSENT, ep_w_hh, ep_b_hh,
            nullptr, nullptr, nullptr, nullptr, nullptr,
            gates_ws, mem, (it == 2) ? out_ep : nullptr);
    }
}

// Round 13
// 1375.222 us; speedup vs baseline: 1.7301x; 1.2973x over previous
//
#include <hip/hip_runtime.h>
#include <hip/hip_bf16.h>

#define HDIM 128
#define G3 384          // 3*H
#define EDIM 300
#define KP 320          // K padded to 10 x 32
#define ASTRIDE 328     // A-tile LDS row stride in bf16 (656B, 16B-aligned)
#define BATCH 64
#define LSTO 1024
#define QLEN 32
#define NSENT 16
#define WGB 16          // batches per scan workgroup
#define HROW 272        // padded h row bytes (17 x 16B)
#define HBUF (WGB * HROW)

typedef float4 f4;
typedef __attribute__((ext_vector_type(8))) short bf16x8;
typedef __attribute__((ext_vector_type(4))) float f32x4;

__device__ __forceinline__ float sigmf(float x) { return 1.0f / (1.0f + __expf(-x)); }
__device__ __forceinline__ float tanhfast(float x) {
    float e = __expf(-2.0f * x);
    return (1.0f - e) / (1.0f + e);
}
__device__ __forceinline__ float bf2f(unsigned short u) {
    return __uint_as_float(((unsigned)u) << 16);
}
__device__ __forceinline__ unsigned short f2bf_u(float f) {
    union { __hip_bfloat16 b; unsigned short s; } u;
    u.b = __float2bfloat16(f);
    return u.s;
}
__device__ __forceinline__ short f2bf_s(float f) {
    union { __hip_bfloat16 b; short s; } u;
    u.b = __float2bfloat16(f);
    return u.s;
}
__device__ __forceinline__ bf16x8 packrow8(const float* p) {
    bf16x8 v;
#pragma unroll
    for (int i = 0; i < 8; i++) v[i] = f2bf_s(p[i]);
    return v;
}
__device__ __forceinline__ unsigned pack2bf(float a, float b) {
    return ((unsigned)f2bf_u(b) << 16) | (unsigned)f2bf_u(a);
}
__device__ __forceinline__ void barrier_nodrain() {
    asm volatile("" ::: "memory");
    __builtin_amdgcn_s_barrier();
    asm volatile("" ::: "memory");
}
__device__ __forceinline__ void lgkm0() {
    asm volatile("s_waitcnt lgkmcnt(0)" ::: "memory");
    __builtin_amdgcn_sched_barrier(0);
}

// ---------------------------------------------------------------------------
// K0: convert w_ih (rows x 300 f32) -> wb (rows x 320 bf16, zero-padded)
// ---------------------------------------------------------------------------
__global__ __launch_bounds__(256) void k_w2bf(
    const float* __restrict__ w, __hip_bfloat16* __restrict__ wb, int rows)
{
    int i = blockIdx.x * 256 + threadIdx.x;
    if (i >= rows * KP) return;
    int r = i / KP, k = i - r * KP;
    float v = (k < EDIM) ? w[(size_t)r * EDIM + k] : 0.f;
    wb[i] = __float2bfloat16(v);
}

// ---------------------------------------------------------------------------
// K1: MFMA gather GEMM. gi[row][g] = b_ih[g] + emb[tok[row]] . w_ih[g]
// 32 rows x 384 gates x K=320 per WG (512 thr, 8 waves). A staged bf16 in
// LDS; B streamed from wb (L2-hot). Frag layouts identical to the verified
// r9/r11 scan patterns (lane l&15 = non-K dim, (l>>4)*8 = K slice).
// ---------------------------------------------------------------------------
__global__ __launch_bounds__(512) void k_gi_mfma(
    const int* __restrict__ toks, int nrows,
    const float* __restrict__ emb,
    const __hip_bfloat16* __restrict__ wb, const float* __restrict__ b_ih,
    __hip_bfloat16* __restrict__ gi)
{
    __shared__ __hip_bfloat16 a_lds[32 * ASTRIDE];   // 20.5 KB
    const int tid = threadIdx.x;
    const int rowbase = blockIdx.x * 32;

    // stage A: 32 rows x KP bf16 (zero-padded K)
    for (int i = tid; i < 32 * KP; i += 512) {
        int r = i / KP, k = i - r * KP;
        int row = rowbase + r;
        float v = 0.f;
        if (k < EDIM) {
            int tok = (row < nrows) ? toks[row] : 0;
            v = emb[(size_t)tok * EDIM + k];
        }
        a_lds[r * ASTRIDE + k] = __float2bfloat16(v);
    }
    __syncthreads();

    const int w8   = tid >> 6;     // wave 0..7 -> gates [48w, 48w+48)
    const int l    = tid & 63;
    const int coln = l & 15;
    const int kg   = l >> 4;

    float bias0 = b_ih[w8 * 48 +  0 + coln];
    float bias1 = b_ih[w8 * 48 + 16 + coln];
    float bias2 = b_ih[w8 * 48 + 32 + coln];

    f32x4 acc[2][3];
#pragma unroll
    for (int mt = 0; mt < 2; mt++) {
        acc[mt][0] = f32x4{bias0, bias0, bias0, bias0};
        acc[mt][1] = f32x4{bias1, bias1, bias1, bias1};
        acc[mt][2] = f32x4{bias2, bias2, bias2, bias2};
    }

    const __hip_bfloat16* bbase = wb + (size_t)(w8 * 48 + coln) * KP + kg * 8;
#pragma unroll
    for (int c = 0; c < KP / 32; ++c) {
        bf16x8 A0 = *reinterpret_cast<const bf16x8*>(
            a_lds + (coln) * ASTRIDE + c * 32 + kg * 8);
        bf16x8 A1 = *reinterpret_cast<const bf16x8*>(
            a_lds + (16 + coln) * ASTRIDE + c * 32 + kg * 8);
        bf16x8 B0 = *reinterpret_cast<const bf16x8*>(bbase + 0 * 16 * KP + c * 32);
        bf16x8 B1 = *reinterpret_cast<const bf16x8*>(bbase + 1 * 16 * KP + c * 32);
        bf16x8 B2 = *reinterpret_cast<const bf16x8*>(bbase + 2 * 16 * KP + c * 32);
        acc[0][0] = __builtin_amdgcn_mfma_f32_16x16x32_bf16(A0, B0, acc[0][0], 0, 0, 0);
        acc[1][0] = __builtin_amdgcn_mfma_f32_16x16x32_bf16(A1, B0, acc[1][0], 0, 0, 0);
        acc[0][1] = __builtin_amdgcn_mfma_f32_16x16x32_bf16(A0, B1, acc[0][1], 0, 0, 0);
        acc[1][1] = __builtin_amdgcn_mfma_f32_16x16x32_bf16(A1, B1, acc[1][1], 0, 0, 0);
        acc[0][2] = __builtin_amdgcn_mfma_f32_16x16x32_bf16(A0, B2, acc[0][2], 0, 0, 0);
        acc[1][2] = __builtin_amdgcn_mfma_f32_16x16x32_bf16(A1, B2, acc[1][2], 0, 0, 0);
    }

#pragma unroll
    for (int mt = 0; mt < 2; mt++) {
#pragma unroll
        for (int nt = 0; nt < 3; nt++) {
            int gate = w8 * 48 + nt * 16 + coln;
#pragma unroll
            for (int q = 0; q < 4; q++) {
                int row = rowbase + mt * 16 + kg * 4 + q;
                if (row < nrows)
                    gi[(size_t)row * G3 + gate] = __float2bfloat16(acc[mt][nt][q]);
            }
        }
    }
}

// ---------------------------------------------------------------------------
// K1b: dense variant, K = 128 (episodic gi from sents) — fp32, small
// ---------------------------------------------------------------------------
__global__ __launch_bounds__(192) void k_gi_dense(
    const float* __restrict__ x, int nrows,
    const float* __restrict__ w_ih, const float* __restrict__ b_ih,
    __hip_bfloat16* __restrict__ gi)
{
    __shared__ alignas(16) float a_lds[32 * HDIM];
    int tid = threadIdx.x;
    int rowbase = blockIdx.x * 32;

    for (int i = tid; i < 32 * 32; i += 192) {   // 32 = 128/4
        int r = i >> 5, e4 = i & 31;
        int row = rowbase + r;
        f4 v;
        if (row < nrows) v = *reinterpret_cast<const f4*>(x + (size_t)row * HDIM + e4 * 4);
        else { v.x = v.y = v.z = v.w = 0.f; }
        *reinterpret_cast<f4*>(a_lds + r * HDIM + e4 * 4) = v;
    }
    __syncthreads();

    int g0 = tid, g1 = tid + 192;
    const float* w0p = w_ih + (size_t)g0 * HDIM;
    const float* w1p = w_ih + (size_t)g1 * HDIM;
    float bb0 = b_ih[g0], bb1 = b_ih[g1];

#pragma unroll
    for (int half = 0; half < 2; half++) {
        float acc0[16], acc1[16];
#pragma unroll
        for (int r = 0; r < 16; r++) { acc0[r] = 0.f; acc1[r] = 0.f; }

        for (int e4 = 0; e4 < 32; ++e4) {
            f4 w0 = *reinterpret_cast<const f4*>(w0p + e4 * 4);
            f4 w1 = *reinterpret_cast<const f4*>(w1p + e4 * 4);
#pragma unroll
            for (int r = 0; r < 16; r++) {
                f4 a = *reinterpret_cast<const f4*>(
                    a_lds + (half * 16 + r) * HDIM + e4 * 4);
                acc0[r] += a.x * w0.x + a.y * w0.y + a.z * w0.z + a.w * w0.w;
                acc1[r] += a.x * w1.x + a.y * w1.y + a.z * w1.z + a.w * w1.w;
            }
        }
#pragma unroll
        for (int r = 0; r < 16; r++) {
            int row = rowbase + half * 16 + r;
            if (row < nrows) {
                gi[(size_t)row * G3 + g0] = __float2bfloat16(acc0[r] + bb0);
                gi[(size_t)row * G3 + g1] = __float2bfloat16(acc1[r] + bb1);
            }
        }
    }
}

// ---------------------------------------------------------------------------
// K2: MFMA-batched GRU scan (unchanged structure from r12 + setprio on MFMA)
// ---------------------------------------------------------------------------
#define SCAN_BODY(TT, TPF, RB, WB, C, P)                                       \
  {                                                                            \
    const int t_ = (TT);                                                       \
    bf16x8 H0 = *reinterpret_cast<const bf16x8*>(h_raw + (RB) + rd0);          \
    bf16x8 H1 = *reinterpret_cast<const bf16x8*>(h_raw + (RB) + rd1);          \
    bf16x8 H2 = *reinterpret_cast<const bf16x8*>(h_raw + (RB) + rd2);          \
    bf16x8 H3 = *reinterpret_cast<const bf16x8*>(h_raw + (RB) + rd3);          \
    {                                                                          \
      const int tp_ = (TPF);                                                   \
      const unsigned short* gp =                                               \
          reinterpret_cast<const unsigned short*>(gib + (size_t)tp_ * G3);     \
      cr##P = *reinterpret_cast<const ushort4*>(gp + j0);                      \
      cz##P = *reinterpret_cast<const ushort4*>(gp + 128 + j0);                \
      cn##P = *reinterpret_cast<const ushort4*>(gp + 256 + j0);                \
      if (MODE == 0) cm##P = mask[bb * LSTO + tp_];                            \
      if (MODE == 2) cw##P = gates[bb * NSENT + tp_];                          \
    }                                                                          \
    f32x4 accr = {br4.x, br4.y, br4.z, br4.w};                                 \
    f32x4 accz = {bz4.x, bz4.y, bz4.z, bz4.w};                                 \
    f32x4 accn = {bn4.x, bn4.y, bn4.z, bn4.w};                                 \
    __builtin_amdgcn_s_setprio(1);                                             \
    accr = __builtin_amdgcn_mfma_f32_16x16x32_bf16(Ar0, H0, accr, 0, 0, 0);    \
    accz = __builtin_amdgcn_mfma_f32_16x16x32_bf16(Az0, H0, accz, 0, 0, 0);    \
    accn = __builtin_amdgcn_mfma_f32_16x16x32_bf16(An0, H0, accn, 0, 0, 0);    \
    accr = __builtin_amdgcn_mfma_f32_16x16x32_bf16(Ar1, H1, accr, 0, 0, 0);    \
    accz = __builtin_amdgcn_mfma_f32_16x16x32_bf16(Az1, H1, accz, 0, 0, 0);    \
    accn = __builtin_amdgcn_mfma_f32_16x16x32_bf16(An1, H1, accn, 0, 0, 0);    \
    accr = __builtin_amdgcn_mfma_f32_16x16x32_bf16(Ar2, H2, accr, 0, 0, 0);    \
    accz = __builtin_amdgcn_mfma_f32_16x16x32_bf16(Az2, H2, accz, 0, 0, 0);    \
    accn = __builtin_amdgcn_mfma_f32_16x16x32_bf16(An2, H2, accn, 0, 0, 0);    \
    accr = __builtin_amdgcn_mfma_f32_16x16x32_bf16(Ar3, H3, accr, 0, 0, 0);    \
    accz = __builtin_amdgcn_mfma_f32_16x16x32_bf16(Az3, H3, accz, 0, 0, 0);    \
    accn = __builtin_amdgcn_mfma_f32_16x16x32_bf16(An3, H3, accn, 0, 0, 0);    \
    __builtin_amdgcn_s_setprio(0);                                             \
    {                                                                          \
      float r0 = sigmf(bf2f(cr##C.x) + accr[0]);                               \
      float r1 = sigmf(bf2f(cr##C.y) + accr[1]);                               \
      float r2 = sigmf(bf2f(cr##C.z) + accr[2]);                               \
      float r3 = sigmf(bf2f(cr##C.w) + accr[3]);                               \
      float z0 = sigmf(bf2f(cz##C.x) + accz[0]);                               \
      float z1 = sigmf(bf2f(cz##C.y) + accz[1]);                               \
      float z2 = sigmf(bf2f(cz##C.z) + accz[2]);                               \
      float z3 = sigmf(bf2f(cz##C.w) + accz[3]);                               \
      float n0 = tanhfast(bf2f(cn##C.x) + r0 * accn[0]);                       \
      float n1 = tanhfast(bf2f(cn##C.y) + r1 * accn[1]);                       \
      float n2 = tanhfast(bf2f(cn##C.z) + r2 * accn[2]);                       \
      float n3 = tanhfast(bf2f(cn##C.w) + r3 * accn[3]);                       \
      float h0 = (1.f - z0) * n0 + z0 * hp0;                                   \
      float h1 = (1.f - z1) * n1 + z1 * hp1;                                   \
      float h2 = (1.f - z2) * n2 + z2 * hp2;                                   \
      float h3 = (1.f - z3) * n3 + z3 * hp3;                                   \
      if (MODE == 2) {                                                         \
        h0 = cw##C * h0 + (1.f - cw##C) * hp0;                                 \
        h1 = cw##C * h1 + (1.f - cw##C) * hp1;                                 \
        h2 = cw##C * h2 + (1.f - cw##C) * hp2;                                 \
        h3 = cw##C * h3 + (1.f - cw##C) * hp3;                                 \
      }                                                                        \
      hp0 = h0; hp1 = h1; hp2 = h2; hp3 = h3;                                  \
    }                                                                          \
    {                                                                          \
      uint2 hw_;                                                               \
      hw_.x = pack2bf(hp0, hp1);                                               \
      hw_.y = pack2bf(hp2, hp3);                                               \
      *reinterpret_cast<uint2*>(h_raw + (WB) + wroff) = hw_;                   \
    }                                                                          \
    if (MODE == 0) {                                                           \
      if (cm##C) {                                                             \
        if (scnt < NSENT) {                                                    \
          float4 v_ = make_float4(hp0, hp1, hp2, hp3);                         \
          *reinterpret_cast<float4*>(                                          \
              sents + ((size_t)bb * NSENT + scnt) * HDIM + j0) = v_;           \
        }                                                                      \
        scnt++;                                                                \
      }                                                                        \
    }                                                                          \
    if (MODE == 1 && t_ == qi) {                                               \
      float4 v_ = make_float4(hp0, hp1, hp2, hp3);                             \
      *reinterpret_cast<float4*>(qv_out + bb * HDIM + j0) = v_;                \
      *reinterpret_cast<float4*>(q_ws + bb * HDIM + j0) = v_;                  \
    }                                                                          \
    if (MODE == 2 && t_ == T - 1) {                                            \
      float4 v_ = make_float4(hp0, hp1, hp2, hp3);                             \
      *reinterpret_cast<float4*>(h_out + bb * HDIM + j0) = v_;                 \
      if (ep_out)                                                              \
        *reinterpret_cast<float4*>(ep_out + bb * HDIM + j0) = v_;              \
    }                                                                          \
    lgkm0();                                                                   \
    barrier_nodrain();                                                         \
  }

template <int MODE>
__global__ __launch_bounds__(512, 2) void k_scan(
    const __hip_bfloat16* __restrict__ gi,   // [BATCH][T][384]
    int T,
    const float* __restrict__ w_hh, const float* __restrict__ b_hh,
    const int* __restrict__ mask,            // MODE 0
    float* __restrict__ sents,               // MODE 0
    const int* __restrict__ qtoks,           // MODE 1
    float* __restrict__ qv_out,              // MODE 1 (d_out)
    float* __restrict__ q_ws,                // MODE 1
    const float* __restrict__ gates,         // MODE 2
    float* __restrict__ h_out,               // MODE 2 (mem ws)
    float* __restrict__ ep_out)              // MODE 2 (d_out, nullable)
{
    __shared__ alignas(16) unsigned char h_raw[2 * HBUF];

    const int tid = threadIdx.x;
    const int w   = tid >> 6;        // wave 0..7
    const int l   = tid & 63;
    const int col = l & 15;          // batch
    const int kg  = l >> 4;          // k-group 0..3
    const int b0  = blockIdx.x * WGB;
    const int bb  = b0 + col;
    const int j0  = 16 * w + 4 * kg; // first of this lane's 4 gate rows

    const float* wr = w_hh + (size_t)(16 * w + col) * HDIM + kg * 8;
    const float* wz = w_hh + (size_t)(128 + 16 * w + col) * HDIM + kg * 8;
    const float* wn = w_hh + (size_t)(256 + 16 * w + col) * HDIM + kg * 8;
    bf16x8 Ar0 = packrow8(wr +  0), Ar1 = packrow8(wr + 32),
           Ar2 = packrow8(wr + 64), Ar3 = packrow8(wr + 96);
    bf16x8 Az0 = packrow8(wz +  0), Az1 = packrow8(wz + 32),
           Az2 = packrow8(wz + 64), Az3 = packrow8(wz + 96);
    bf16x8 An0 = packrow8(wn +  0), An1 = packrow8(wn + 32),
           An2 = packrow8(wn + 64), An3 = packrow8(wn + 96);
    asm volatile("" : "+v"(Ar0), "+v"(Ar1), "+v"(Ar2), "+v"(Ar3));
    asm volatile("" : "+v"(Az0), "+v"(Az1), "+v"(Az2), "+v"(Az3));
    asm volatile("" : "+v"(An0), "+v"(An1), "+v"(An2), "+v"(An3));

    f4 br4 = *reinterpret_cast<const f4*>(b_hh + j0);
    f4 bz4 = *reinterpret_cast<const f4*>(b_hh + 128 + j0);
    f4 bn4 = *reinterpret_cast<const f4*>(b_hh + 256 + j0);

    const int rd0 = col * HROW + 0 * 64 + kg * 16;
    const int rd1 = col * HROW + 1 * 64 + kg * 16;
    const int rd2 = col * HROW + 2 * 64 + kg * 16;
    const int rd3 = col * HROW + 3 * 64 + kg * 16;
    const int wroff = col * HROW + j0 * 2;

    for (int i = tid; i < 2 * HBUF / 4; i += 512)
        reinterpret_cast<unsigned*>(h_raw)[i] = 0u;

    int qi = QLEN - 1;
    if (MODE == 1) {
        for (int t2 = 0; t2 < QLEN - 1; t2++)
            if (qtoks[bb * QLEN + t2 + 1] == 0) { qi = t2; break; }
    }
    int scnt = 0;

    const __hip_bfloat16* gib = gi + (size_t)bb * T * G3;
    ushort4 crA, czA, cnA, crB, czB, cnB;
    int cmA = 0, cmB = 0;
    float cwA = 0.f, cwB = 0.f;
    {
        const unsigned short* gp = reinterpret_cast<const unsigned short*>(gib);
        crA = *reinterpret_cast<const ushort4*>(gp + j0);
        czA = *reinterpret_cast<const ushort4*>(gp + 128 + j0);
        cnA = *reinterpret_cast<const ushort4*>(gp + 256 + j0);
        if (MODE == 0) cmA = mask[bb * LSTO];
        if (MODE == 2) cwA = gates[bb * NSENT];
    }
    float hp0 = 0.f, hp1 = 0.f, hp2 = 0.f, hp3 = 0.f;
    __syncthreads();

    for (int t = 0; t < T; t += 2) {
        SCAN_BODY(t,     t + 1,                     0,    HBUF, A, B)
        SCAN_BODY(t + 1, (t + 2 < T ? t + 2 : t+1), HBUF, 0,    B, A)
    }
}

// ---------------------------------------------------------------------------
// K3: attention gates.  WG per batch, 128 threads = (16 t) x (8 segments).
// ---------------------------------------------------------------------------
__global__ __launch_bounds__(128) void k_gates(
    const float* __restrict__ sents, const float* __restrict__ q_ws,
    const float* __restrict__ mem, const float* __restrict__ gate_w,
    const float* __restrict__ gate_b,
    float* __restrict__ gates_ws, float* __restrict__ gout)
{
    int b = blockIdx.x, tid = threadIdx.x;
    int t = tid >> 3, s = tid & 7;
    float p = 0.f;
    const float* sv = sents + ((size_t)b * NSENT + t) * HDIM;
    for (int jj = 0; jj < 16; jj++) {
        int j = s * 16 + jj;
        float S = sv[j], Q = q_ws[b * HDIM + j], M = mem[b * HDIM + j];
        float dq = S - Q, dm = S - M;
        p += (S * Q) * gate_w[j] + (S * M) * gate_w[HDIM + j] +
             (dq * dq) * gate_w[2 * HDIM + j] + (dm * dm) * gate_w[3 * HDIM + j];
    }
    __shared__ float red[16][8];
    red[t][s] = p;
    __syncthreads();
    if (s == 0) {
        float sum = 0.f;
        for (int k = 0; k < 8; k++) sum += red[t][k];
        float gt = sigmf(sum + gate_b[0]);
        gates_ws[b * NSENT + t] = gt;
        if (gout) gout[b * NSENT + t] = gt;
    }
}

// ---------------------------------------------------------------------------
extern "C" void kernel_launch(void* const* d_in, const int* in_sizes, int n_in,
                              void* d_out, int out_size, void* d_ws, size_t ws_size,
                              hipStream_t stream)
{
    const int*   x_sto    = (const int*)d_in[0];
    const int*   x_mask   = (const int*)d_in[1];
    const int*   x_q      = (const int*)d_in[2];
    const float* emb      = (const float*)d_in[4];
    const float* enc_w_ih = (const float*)d_in[5];
    const float* enc_w_hh = (const float*)d_in[6];
    const float* enc_b_ih = (const float*)d_in[7];
    const float* enc_b_hh = (const float*)d_in[8];
    const float* gate_w   = (const float*)d_in[9];
    const float* gate_b   = (const float*)d_in[10];
    const float* ep_w_ih  = (const float*)d_in[11];
    const float* ep_w_hh  = (const float*)d_in[12];
    const float* ep_b_ih  = (const float*)d_in[13];
    const float* ep_b_hh  = (const float*)d_in[14];

    float* out_q  = (float*)d_out;                       // (64,128)
    float* out_ep = (float*)d_out + BATCH * HDIM;        // (1,64,128)
    float* out_g  = (float*)d_out + 2 * BATCH * HDIM;    // (64,16)

    char* ws = (char*)d_ws;
    size_t off = 0;
    auto alloc = [&](size_t bytes) {
        void* p = ws + off;
        off += (bytes + 255) & ~(size_t)255;
        return p;
    };
    __hip_bfloat16* gi_sto = (__hip_bfloat16*)alloc((size_t)BATCH * LSTO * G3 * 2);
    __hip_bfloat16* gi_q   = (__hip_bfloat16*)alloc((size_t)BATCH * QLEN * G3 * 2);
    __hip_bfloat16* gi_ep  = (__hip_bfloat16*)alloc((size_t)BATCH * NSENT * G3 * 2);
    __hip_bfloat16* wb_enc = (__hip_bfloat16*)alloc((size_t)G3 * KP * 2);
    float* sents    = (float*)alloc((size_t)BATCH * NSENT * HDIM * 4);
    float* q_ws     = (float*)alloc((size_t)BATCH * HDIM * 4);
    float* mem      = (float*)alloc((size_t)BATCH * HDIM * 4);
    float* gates_ws = (float*)alloc((size_t)BATCH * NSENT * 4);
    (void)ws_size; (void)in_sizes; (void)n_in; (void)out_size;

    // Phase A0: convert enc_w_ih to padded bf16
    k_w2bf<<<(G3 * KP + 255) / 256, 256, 0, stream>>>(enc_w_ih, wb_enc, G3);

    // Phase A: input-projection GEMMs via MFMA
    k_gi_mfma<<<(BATCH * LSTO) / 32, 512, 0, stream>>>(
        x_sto, BATCH * LSTO, emb, wb_enc, enc_b_ih, gi_sto);
    k_gi_mfma<<<(BATCH * QLEN) / 32, 512, 0, stream>>>(
        x_q, BATCH * QLEN, emb, wb_enc, enc_b_ih, gi_q);

    // Phase B: story scan (writes sents), question scan (writes q_vecs)
    k_scan<0><<<BATCH / WGB, 512, 0, stream>>>(
        gi_sto, LSTO, enc_w_hh, enc_b_hh,
        x_mask, sents, nullptr, nullptr, nullptr, nullptr, nullptr, nullptr);
    k_scan<1><<<BATCH / WGB, 512, 0, stream>>>(
        gi_q, QLEN, enc_w_hh, enc_b_hh,
        nullptr, nullptr, x_q, out_q, q_ws, nullptr, nullptr, nullptr);

    // Phase C: episodic memory, 3 iterations
    k_gi_dense<<<(BATCH * NSENT) / 32, 192, 0, stream>>>(
        sents, BATCH * NSENT, ep_w_ih, ep_b_ih, gi_ep);

    for (int it = 0; it < 3; ++it) {
        const float* msrc = (it == 0) ? q_ws : mem;
        k_gates<<<BATCH, 128, 0, stream>>>(
            sents, q_ws, msrc, gate_w, gate_b, gates_ws,
            (it == 2) ? out_g : nullptr);
        k_scan<2><<<BATCH / WGB, 512, 0, stream>>>(
            gi_ep, NSENT, ep_w_hh, ep_b_hh,
            nullptr, nullptr, nullptr, nullptr, nullptr,
            gates_ws, mem, (it == 2) ? out_ep : nullptr);
    }
}